// Round 7
// baseline (198.286 us; speedup 1.0000x reference)
//
#include <hip/hip_runtime.h>

#define TT 2048
#define BB 512

#if __has_builtin(__builtin_amdgcn_exp2f)
__device__ __forceinline__ float fexp2(float x){ return __builtin_amdgcn_exp2f(x); }
#else
__device__ __forceinline__ float fexp2(float x){ return exp2f(x); }
#endif
#if __has_builtin(__builtin_amdgcn_logf)
__device__ __forceinline__ float flog2(float x){ return __builtin_amdgcn_logf(x); }
#else
__device__ __forceinline__ float flog2(float x){ return log2f(x); }
#endif
__device__ __forceinline__ float frcp(float x){ return __builtin_amdgcn_rcpf(x); }

// ---- fp8 e4m3 pack/unpack (OCP, gfx950 HW cvt) ----
#if __has_builtin(__builtin_amdgcn_cvt_pk_fp8_f32) && __has_builtin(__builtin_amdgcn_cvt_pk_f32_fp8)
__device__ __forceinline__ unsigned enc_lo(float a,float b,unsigned old){
  return (unsigned)__builtin_amdgcn_cvt_pk_fp8_f32(a,b,(int)old,false);
}
__device__ __forceinline__ unsigned enc_hi(float a,float b,unsigned old){
  return (unsigned)__builtin_amdgcn_cvt_pk_fp8_f32(a,b,(int)old,true);
}
__device__ __forceinline__ void dec_lo(unsigned w,float&x,float&y){
  auto r=__builtin_amdgcn_cvt_pk_f32_fp8((int)w,false); x=r[0]; y=r[1];
}
__device__ __forceinline__ void dec_hi(unsigned w,float&x,float&y){
  auto r=__builtin_amdgcn_cvt_pk_f32_fp8((int)w,true); x=r[0]; y=r[1];
}
#else
__device__ __forceinline__ unsigned enc1(float x){
  if (!(x > 0x1p-10f)) return 0u;
  unsigned b = __float_as_uint(x) + 0x80000u;
  int e = (int)((b>>23)&0xFF) - 127;
  if (e < -6){ int m = (int)(x*512.0f + 0.5f); return (unsigned)m; }
  if (e > 8) return 0x7Eu;
  return (unsigned)(((e+7)<<3) | ((b>>20)&7));
}
__device__ __forceinline__ float dec1(unsigned byte){
  unsigned e=(byte>>3)&0xF, m=byte&7;
  if (e==0) return (float)m * 0x1p-9f;
  return __uint_as_float(((e+120u)<<23)|(m<<20));
}
__device__ __forceinline__ unsigned enc_lo(float a,float b,unsigned old){
  return (old & 0xFFFF0000u) | enc1(a) | (enc1(b)<<8);
}
__device__ __forceinline__ unsigned enc_hi(float a,float b,unsigned old){
  return (old & 0x0000FFFFu) | (enc1(a)<<16) | (enc1(b)<<24);
}
__device__ __forceinline__ void dec_lo(unsigned w,float&x,float&y){ x=dec1(w&0xFF); y=dec1((w>>8)&0xFF); }
__device__ __forceinline__ void dec_hi(unsigned w,float&x,float&y){ x=dec1((w>>16)&0xFF); y=dec1(w>>24); }
#endif

__device__ __forceinline__ float lse2_4(float x0,float x1,float x2,float x3){
  float m = fmaxf(fmaxf(x0,x1),fmaxf(x2,x3));
  float e = fexp2(x0-m)+fexp2(x1-m)+fexp2(x2-m)+fexp2(x3-m);
  return m + flog2(e);
}

// One dialog = 4 blocks of 256 threads; each block covers 512 timesteps.
// Last-arriving block combines the 4 partial matrices and writes out[b].
__global__ __launch_bounds__(256) void crf_part(
    const float* __restrict__ trans,      // [6,6]
    const float* __restrict__ w,          // [4]
    const float* __restrict__ mult,       // [4,4]
    const float* __restrict__ out_table,  // [V,4]
    const float* __restrict__ bias,       // [B,T]
    const int*   __restrict__ sentence,   // [B,T]
    const int*   __restrict__ tags,       // [B,T]
    float* __restrict__ out,              // [B]
    int*   __restrict__ counters,         // [B]   (zeroed per launch)
    float* __restrict__ partM,            // [B][4][20]
    float* __restrict__ partG)            // [B][4]
{
  constexpr float INVLN2 = 1.4426950408889634f;
  constexpr float LN2    = 0.6931471805599453f;
  const int blk = blockIdx.x;
  const int b   = blk >> 2;
  const int p   = blk & 3;
  const int tid = threadIdx.x;

  // Te fp8: 512 granules of 16B, swizzled granule = tl ^ ((tl>>3)&7)
  __shared__ __align__(16) char  s_te[8192];
  __shared__ __align__(16) float s_c[512];
  __shared__ float s_PAm[64*16];
  __shared__ float s_PAs[64*4];
  __shared__ float s_M[16];
  __shared__ float s_tr[36];
  __shared__ float s_wgold[4];
  __shared__ int   s_lastf;
  float* s_PBm = (float*)s_te;            // aliased after phase-1 reads complete
  float* s_PBs = (float*)(s_te + 4096);

  // ---- per-thread constants ----
  float trans2[16]; float t2max = -1e30f;
  #pragma unroll
  for (int i=0;i<4;i++)
    #pragma unroll
    for (int k=0;k<4;k++){
      float v = trans[i*6+k]*INVLN2;
      trans2[i*4+k] = v; t2max = fmaxf(t2max, v);
    }
  const float T144 = t2max + 1.4427f;

  float M[16];
  {
    float e[16]; float cs[4]={0.f,0.f,0.f,0.f};
    #pragma unroll
    for (int i=0;i<4;i++)
      #pragma unroll
      for (int j=0;j<4;j++){
        float v = fexp2(mult[i*4+j]*INVLN2);
        e[i*4+j]=v; cs[j]+=v;
      }
    #pragma unroll
    for (int j=0;j<4;j++) cs[j]=frcp(cs[j]);
    #pragma unroll
    for (int i=0;i<4;i++)
      #pragma unroll
      for (int j=0;j<4;j++)
        M[i*4+j] = (i==j) ? -1.f : e[i*4+j]*cs[j];
  }
  const float wc0=w[0]*2.f*INVLN2, wc1=w[1]*2.f*INVLN2,
              wc2=w[2]*2.f*INVLN2, wc3=w[3]*2.f*INVLN2;
  if (tid<36) s_tr[tid]=trans[tid];
  if (tid==0){
    #pragma unroll
    for (int i=0;i<16;i++) s_M[i]=M[i];
  }
  __syncthreads();

  // ---- phase 0: 2 consecutive t per thread; fp8 Te + gold partial ----
  float gold = 0.f;
  {
    const int t0    = tid<<1;
    const int gbase = b*TT + (p<<9) + t0;
    float2 bb2 = *reinterpret_cast<const float2*>(bias + gbase);
    int2  sen2 = *reinterpret_cast<const int2*>(sentence + gbase);
    int2  tg2  = *reinterpret_cast<const int2*>(tags + gbase);
    float4 ftA = *reinterpret_cast<const float4*>(out_table + (size_t)sen2.x*4);
    float4 ftB = *reinterpret_cast<const float4*>(out_table + (size_t)sen2.y*4);

    int pv0;
    if ((tid & 63)==0) pv0 = (p==0 && t0==0) ? 4 : tags[gbase-1];
    else               pv0 = __shfl_up(tg2.y, 1);

    #pragma unroll
    for (int e=0;e<2;e++){
      const int tl = t0 + e;
      float bb   = e ? bb2.y : bb2.x;
      float4 f4e = e ? ftB   : ftA;
      int tg     = e ? tg2.y : tg2.x;
      int pv     = e ? tg2.x : pv0;

      float bh = bb-0.5f;
      float y0=fexp2(bh*wc0); float sh0=bb*(y0-1.f)*frcp(y0+1.f);
      float y1=fexp2(bh*wc1); float sh1=bb*(y1-1.f)*frcp(y1+1.f);
      float y2=fexp2(bh*wc2); float sh2v=bb*(y2-1.f)*frcp(y2+1.f);
      float y3=fexp2(bh*wc3); float sh3=bb*(y3-1.f)*frcp(y3+1.f);
      float s20=sh0*INVLN2, s21=sh1*INVLN2, s22=sh2v*INVLN2, s23=sh3*INVLN2;
      float f20=f4e.x*INVLN2, f21=f4e.y*INVLN2, f22=f4e.z*INVLN2, f23=f4e.w*INVLN2;

      float ct  = fmaxf(fmaxf(f20,f21),fmaxf(f22,f23)) + T144;
      float off = 8.0f - ct;
      float o0=f20+off, o1=f21+off, o2=f22+off, o3=f23+off;
      float a00=fexp2(fmaf(M[ 0],s20,trans2[ 0]+o0));
      float a01=fexp2(fmaf(M[ 1],s21,trans2[ 1]+o0));
      float a02=fexp2(fmaf(M[ 2],s22,trans2[ 2]+o0));
      float a03=fexp2(fmaf(M[ 3],s23,trans2[ 3]+o0));
      float a10=fexp2(fmaf(M[ 4],s20,trans2[ 4]+o1));
      float a11=fexp2(fmaf(M[ 5],s21,trans2[ 5]+o1));
      float a12=fexp2(fmaf(M[ 6],s22,trans2[ 6]+o1));
      float a13=fexp2(fmaf(M[ 7],s23,trans2[ 7]+o1));
      float a20=fexp2(fmaf(M[ 8],s20,trans2[ 8]+o2));
      float a21=fexp2(fmaf(M[ 9],s21,trans2[ 9]+o2));
      float a22=fexp2(fmaf(M[10],s22,trans2[10]+o2));
      float a23=fexp2(fmaf(M[11],s23,trans2[11]+o2));
      float a30=fexp2(fmaf(M[12],s20,trans2[12]+o3));
      float a31=fexp2(fmaf(M[13],s21,trans2[13]+o3));
      float a32=fexp2(fmaf(M[14],s22,trans2[14]+o3));
      float a33=fexp2(fmaf(M[15],s23,trans2[15]+o3));

      unsigned d0=enc_lo(a00,a01,0u); d0=enc_hi(a02,a03,d0);
      unsigned d1=enc_lo(a10,a11,0u); d1=enc_hi(a12,a13,d1);
      unsigned d2=enc_lo(a20,a21,0u); d2=enc_hi(a22,a23,d2);
      unsigned d3=enc_lo(a30,a31,0u); d3=enc_hi(a32,a33,d3);
      int g = (tl ^ ((tl>>3)&7)) << 4;
      *reinterpret_cast<uint4*>(s_te+g) = make_uint4(d0,d1,d2,d3);
      s_c[tl] = ct;

      // gold
      float term;
      if (pv>=4){                           // only at global t==0
        term = s_tr[tg*6+4];
      } else {
        float shp=(pv==0)?sh0:(pv==1)?sh1:(pv==2)?sh2v:sh3;
        term = s_tr[tg*6+pv] + shp*s_M[tg*4+pv];
      }
      term += (tg==0)?f4e.x:(tg==1)?f4e.y:(tg==2)?f4e.z:f4e.w;
      if (p==3 && tl==511) term += s_tr[30+tg];
      gold += term;
    }
    if (p==0 && tid==0){   // plant identity at t=0
      *reinterpret_cast<uint4*>(s_te) = make_uint4(0x38u,0x3800u,0x380000u,0x38000000u);
      s_c[0] = 8.0f;
    }
  }
  #pragma unroll
  for (int off=32; off>0; off>>=1) gold += __shfl_down(gold, off);
  if ((tid & 63)==0) s_wgold[tid>>6] = gold;
  __syncthreads();

  // ---- phase 1: 64 chunks x 8 steps; fp8 matvec, renorm once at chunk end ----
  {
    int c = tid>>2, j = tid&3;
    int t0c = c<<3;
    int K = c & 7;
    float p0=(j==0)?1.f:0.f, p1=(j==1)?1.f:0.f, p2=(j==2)?1.f:0.f, p3=(j==3)?1.f:0.f;
    #pragma unroll
    for (int s=0;s<8;s++){
      int g = ((t0c+s) ^ K) << 4;
      uint4 q = *reinterpret_cast<const uint4*>(s_te + g);
      float e0,e1,e2,e3;
      dec_lo(q.x,e0,e1); dec_hi(q.x,e2,e3);
      float n0 = fmaf(e0,p0, e1*p1); n0 = fmaf(e2,p2,n0); n0 = fmaf(e3,p3,n0);
      dec_lo(q.y,e0,e1); dec_hi(q.y,e2,e3);
      float n1 = fmaf(e0,p0, e1*p1); n1 = fmaf(e2,p2,n1); n1 = fmaf(e3,p3,n1);
      dec_lo(q.z,e0,e1); dec_hi(q.z,e2,e3);
      float n2 = fmaf(e0,p0, e1*p1); n2 = fmaf(e2,p2,n2); n2 = fmaf(e3,p3,n2);
      dec_lo(q.w,e0,e1); dec_hi(q.w,e2,e3);
      float n3 = fmaf(e0,p0, e1*p1); n3 = fmaf(e2,p2,n3); n3 = fmaf(e3,p3,n3);
      p0=n0; p1=n1; p2=n2; p3=n3;
    }
    float sum = fmaxf((p0+p1)+(p2+p3), 1e-30f);
    float inv = frcp(sum);
    const float4* cp = reinterpret_cast<const float4*>(s_c + t0c);
    float4 ca=cp[0], cb=cp[1];
    float L = flog2(sum)
            + ((ca.x+ca.y)+(ca.z+ca.w)) + ((cb.x+cb.y)+(cb.z+cb.w)) - 64.0f;
    s_PAm[c*16 + 0*4 + j] = p0*inv;
    s_PAm[c*16 + 1*4 + j] = p1*inv;
    s_PAm[c*16 + 2*4 + j] = p2*inv;
    s_PAm[c*16 + 3*4 + j] = p3*inv;
    s_PAs[c*4 + j] = L;
  }
  __syncthreads();   // all s_te reads done before PB alias writes

  // ---- phase 2: tree combine 64 -> 1 (6 levels) ----
  float *srcM = s_PAm, *srcS = s_PAs, *dstM = s_PBm, *dstS = s_PBs;
  #pragma unroll 1
  for (int n=32; n>=1; n>>=1){
    if (tid < n*4){
      int q = tid>>2, j = tid&3;
      const float* Am = srcM + (2*q)*16;
      const float* As = srcS + (2*q)*4;
      const float* Bm = Am + 16;
      const float* Bs = As + 4;
      float b0=Bs[0], b1=Bs[1], b2=Bs[2], b3=Bs[3];
      float m = fmaxf(fmaxf(b0,b1), fmaxf(b2,b3));
      float a0 = Am[0*4+j]*fexp2(b0-m);
      float a1 = Am[1*4+j]*fexp2(b1-m);
      float a2 = Am[2*4+j]*fexp2(b2-m);
      float a3 = Am[3*4+j]*fexp2(b3-m);
      float c0 = fmaf(Bm[ 0],a0, fmaf(Bm[ 1],a1, fmaf(Bm[ 2],a2, Bm[ 3]*a3)));
      float c1 = fmaf(Bm[ 4],a0, fmaf(Bm[ 5],a1, fmaf(Bm[ 6],a2, Bm[ 7]*a3)));
      float c2 = fmaf(Bm[ 8],a0, fmaf(Bm[ 9],a1, fmaf(Bm[10],a2, Bm[11]*a3)));
      float c3 = fmaf(Bm[12],a0, fmaf(Bm[13],a1, fmaf(Bm[14],a2, Bm[15]*a3)));
      float ssum = fmaxf((c0+c1)+(c2+c3), 1e-37f);
      float inv = frcp(ssum);
      dstM[q*16+0*4+j] = c0*inv;
      dstM[q*16+1*4+j] = c1*inv;
      dstM[q*16+2*4+j] = c2*inv;
      dstM[q*16+3*4+j] = c3*inv;
      dstS[q*4+j] = m + As[j] + flog2(ssum);
    }
    __syncthreads();
    float* tm;
    tm=srcM; srcM=dstM; dstM=tm;
    tm=srcS; srcS=dstS; dstS=tm;
  }

  // ---- publish this part's 20 floats + gold ----
  const int idx = (b<<2) | p;
  if (tid < 16)       partM[idx*20 + tid] = srcM[tid];
  else if (tid < 20)  partM[idx*20 + tid] = srcS[tid-16];
  if (tid == 0)
    partG[idx] = ((s_wgold[0]+s_wgold[1])+(s_wgold[2]+s_wgold[3]));
  __threadfence();
  __syncthreads();
  if (tid==0) s_lastf = (atomicAdd(&counters[b], 1) == 3);
  __syncthreads();

  // ---- last block of this dialog: combine 4 parts, finish ----
  if (s_lastf){
    __threadfence();
    if (tid < 4){
      int j = tid;
      volatile const float* P0 = partM + (size_t)(b<<2)*20;
      float c0=P0[0*4+j], c1=P0[1*4+j], c2=P0[2*4+j], c3=P0[3*4+j];
      float Lc=P0[16+j];
      #pragma unroll 1
      for (int q=1;q<4;q++){
        volatile const float* Bq = partM + (size_t)((b<<2)+q)*20;
        float Bs0=Bq[16], Bs1=Bq[17], Bs2=Bq[18], Bs3=Bq[19];
        float m = fmaxf(fmaxf(Bs0,Bs1), fmaxf(Bs2,Bs3));
        float a0=c0*fexp2(Bs0-m), a1=c1*fexp2(Bs1-m),
              a2=c2*fexp2(Bs2-m), a3=c3*fexp2(Bs3-m);
        float n0 = fmaf(Bq[ 0],a0, fmaf(Bq[ 1],a1, fmaf(Bq[ 2],a2, Bq[ 3]*a3)));
        float n1 = fmaf(Bq[ 4],a0, fmaf(Bq[ 5],a1, fmaf(Bq[ 6],a2, Bq[ 7]*a3)));
        float n2 = fmaf(Bq[ 8],a0, fmaf(Bq[ 9],a1, fmaf(Bq[10],a2, Bq[11]*a3)));
        float n3 = fmaf(Bq[12],a0, fmaf(Bq[13],a1, fmaf(Bq[14],a2, Bq[15]*a3)));
        float ss = fmaxf((n0+n1)+(n2+n3), 1e-37f);
        float iv = frcp(ss);
        c0=n0*iv; c1=n1*iv; c2=n2*iv; c3=n3*iv;
        Lc += m + flog2(ss);
      }
      s_PAm[0*4+j]=c0; s_PAm[1*4+j]=c1; s_PAm[2*4+j]=c2; s_PAm[3*4+j]=c3;
      s_PAs[j]=Lc;
    }
    __syncthreads();
    if (tid==0){
      const float* Pf = s_PAm;
      const float* Ls = s_PAs;
      int s0 = sentence[b*TT];
      float4 f0 = *reinterpret_cast<const float4*>(out_table + (size_t)s0*4);
      float a0 = (s_tr[ 4] + f0.x)*INVLN2;
      float a1 = (s_tr[10] + f0.y)*INVLN2;
      float a2 = (s_tr[16] + f0.z)*INVLN2;
      float a3 = (s_tr[22] + f0.w)*INVLN2;
      float u0 = Ls[0]+a0, u1 = Ls[1]+a1, u2 = Ls[2]+a2, u3 = Ls[3]+a3;
      float m2 = fmaxf(fmaxf(u0,u1), fmaxf(u2,u3));
      float e0 = fexp2(u0-m2), e1 = fexp2(u1-m2), e2 = fexp2(u2-m2), e3 = fexp2(u3-m2);
      float v0 = fmaf(Pf[ 0],e0, fmaf(Pf[ 1],e1, fmaf(Pf[ 2],e2, Pf[ 3]*e3)));
      float v1 = fmaf(Pf[ 4],e0, fmaf(Pf[ 5],e1, fmaf(Pf[ 6],e2, Pf[ 7]*e3)));
      float v2 = fmaf(Pf[ 8],e0, fmaf(Pf[ 9],e1, fmaf(Pf[10],e2, Pf[11]*e3)));
      float v3 = fmaf(Pf[12],e0, fmaf(Pf[13],e1, fmaf(Pf[14],e2, Pf[15]*e3)));
      float n0 = flog2(v0)+m2, n1 = flog2(v1)+m2, n2 = flog2(v2)+m2, n3 = flog2(v3)+m2;
      float fwd2 = lse2_4(n0+s_tr[30]*INVLN2, n1+s_tr[31]*INVLN2,
                          n2+s_tr[32]*INVLN2, n3+s_tr[33]*INVLN2);
      volatile const float* Gp = partG + (size_t)(b<<2);
      float g = (Gp[0]+Gp[1])+(Gp[2]+Gp[3]);
      out[b] = fwd2*LN2 - g;
    }
  }
}

extern "C" void kernel_launch(void* const* d_in, const int* in_sizes, int n_in,
                              void* d_out, int out_size, void* d_ws, size_t ws_size,
                              hipStream_t stream) {
  const float* trans     = (const float*)d_in[0];
  const float* w         = (const float*)d_in[1];
  const float* mult      = (const float*)d_in[2];
  const float* out_table = (const float*)d_in[3];
  const float* bias      = (const float*)d_in[4];
  const int*   sentence  = (const int*)d_in[5];
  const int*   tags      = (const int*)d_in[6];
  int*   counters = (int*)d_ws;
  float* partM    = (float*)((char*)d_ws + 2048);
  float* partG    = (float*)((char*)d_ws + 2048 + BB*4*20*sizeof(float));
  hipMemsetAsync(d_ws, 0, 2048, stream);
  crf_part<<<BB*4, 256, 0, stream>>>(trans, w, mult, out_table, bias, sentence, tags,
                                     (float*)d_out, counters, partM, partG);
}

// Round 8
// 21.967 us; speedup vs baseline: 9.0265x; 9.0265x over previous
//
#include <hip/hip_runtime.h>

#define TT 2048
#define BB 512

#if __has_builtin(__builtin_amdgcn_exp2f)
__device__ __forceinline__ float fexp2(float x){ return __builtin_amdgcn_exp2f(x); }
#else
__device__ __forceinline__ float fexp2(float x){ return exp2f(x); }
#endif
#if __has_builtin(__builtin_amdgcn_logf)
__device__ __forceinline__ float flog2(float x){ return __builtin_amdgcn_logf(x); }
#else
__device__ __forceinline__ float flog2(float x){ return log2f(x); }
#endif
__device__ __forceinline__ float frcp(float x){ return __builtin_amdgcn_rcpf(x); }

// ---- fp8 e4m3 pack/unpack (OCP, gfx950 HW cvt) ----
#if __has_builtin(__builtin_amdgcn_cvt_pk_fp8_f32) && __has_builtin(__builtin_amdgcn_cvt_pk_f32_fp8)
__device__ __forceinline__ unsigned enc_lo(float a,float b,unsigned old){
  return (unsigned)__builtin_amdgcn_cvt_pk_fp8_f32(a,b,(int)old,false);
}
__device__ __forceinline__ unsigned enc_hi(float a,float b,unsigned old){
  return (unsigned)__builtin_amdgcn_cvt_pk_fp8_f32(a,b,(int)old,true);
}
__device__ __forceinline__ void dec_lo(unsigned w,float&x,float&y){
  auto r=__builtin_amdgcn_cvt_pk_f32_fp8((int)w,false); x=r[0]; y=r[1];
}
__device__ __forceinline__ void dec_hi(unsigned w,float&x,float&y){
  auto r=__builtin_amdgcn_cvt_pk_f32_fp8((int)w,true); x=r[0]; y=r[1];
}
#else
__device__ __forceinline__ unsigned enc1(float x){
  if (!(x > 0x1p-10f)) return 0u;
  unsigned b = __float_as_uint(x) + 0x80000u;
  int e = (int)((b>>23)&0xFF) - 127;
  if (e < -6){ int m = (int)(x*512.0f + 0.5f); return (unsigned)m; }
  if (e > 8) return 0x7Eu;
  return (unsigned)(((e+7)<<3) | ((b>>20)&7));
}
__device__ __forceinline__ float dec1(unsigned byte){
  unsigned e=(byte>>3)&0xF, m=byte&7;
  if (e==0) return (float)m * 0x1p-9f;
  return __uint_as_float(((e+120u)<<23)|(m<<20));
}
__device__ __forceinline__ unsigned enc_lo(float a,float b,unsigned old){
  return (old & 0xFFFF0000u) | enc1(a) | (enc1(b)<<8);
}
__device__ __forceinline__ unsigned enc_hi(float a,float b,unsigned old){
  return (old & 0x0000FFFFu) | (enc1(a)<<16) | (enc1(b)<<24);
}
__device__ __forceinline__ void dec_lo(unsigned w,float&x,float&y){ x=dec1(w&0xFF); y=dec1((w>>8)&0xFF); }
__device__ __forceinline__ void dec_hi(unsigned w,float&x,float&y){ x=dec1((w>>16)&0xFF); y=dec1(w>>24); }
#endif

__device__ __forceinline__ float lse2_4(float x0,float x1,float x2,float x3){
  float m = fmaxf(fmaxf(x0,x1),fmaxf(x2,x3));
  float e = fexp2(x0-m)+fexp2(x1-m)+fexp2(x2-m)+fexp2(x3-m);
  return m + flog2(e);
}

// Kernel 1: one dialog = 4 blocks of 256 threads; each block reduces its 512
// timesteps to a 4x4 prob-matrix + 4 log2-scales + gold partial -> d_ws.
// No atomics/fences: the kernel boundary is the synchronization.
__global__ __launch_bounds__(256) void crf_part(
    const float* __restrict__ trans,      // [6,6]
    const float* __restrict__ w,          // [4]
    const float* __restrict__ mult,       // [4,4]
    const float* __restrict__ out_table,  // [V,4]
    const float* __restrict__ bias,       // [B,T]
    const int*   __restrict__ sentence,   // [B,T]
    const int*   __restrict__ tags,       // [B,T]
    float* __restrict__ partM,            // [B][4][20]
    float* __restrict__ partG)            // [B][4]
{
  constexpr float INVLN2 = 1.4426950408889634f;
  const int blk = blockIdx.x;
  const int b   = blk >> 2;
  const int p   = blk & 3;
  const int tid = threadIdx.x;

  __shared__ __align__(16) char  s_te[8192];   // fp8 Te, granule = tl ^ ((tl>>3)&7)
  __shared__ __align__(16) float s_c[512];
  __shared__ float s_PAm[64*16];
  __shared__ float s_PAs[64*4];
  __shared__ float s_M[16];
  __shared__ float s_tr[36];
  __shared__ float s_wgold[4];
  float* s_PBm = (float*)s_te;                 // aliased after phase-1 reads
  float* s_PBs = (float*)(s_te + 4096);

  float trans2[16]; float t2max = -1e30f;
  #pragma unroll
  for (int i=0;i<4;i++)
    #pragma unroll
    for (int k=0;k<4;k++){
      float v = trans[i*6+k]*INVLN2;
      trans2[i*4+k] = v; t2max = fmaxf(t2max, v);
    }
  const float T144 = t2max + 1.4427f;

  float M[16];
  {
    float e[16]; float cs[4]={0.f,0.f,0.f,0.f};
    #pragma unroll
    for (int i=0;i<4;i++)
      #pragma unroll
      for (int j=0;j<4;j++){
        float v = fexp2(mult[i*4+j]*INVLN2);
        e[i*4+j]=v; cs[j]+=v;
      }
    #pragma unroll
    for (int j=0;j<4;j++) cs[j]=frcp(cs[j]);
    #pragma unroll
    for (int i=0;i<4;i++)
      #pragma unroll
      for (int j=0;j<4;j++)
        M[i*4+j] = (i==j) ? -1.f : e[i*4+j]*cs[j];
  }
  const float wc0=w[0]*2.f*INVLN2, wc1=w[1]*2.f*INVLN2,
              wc2=w[2]*2.f*INVLN2, wc3=w[3]*2.f*INVLN2;
  if (tid<36) s_tr[tid]=trans[tid];
  if (tid==0){
    #pragma unroll
    for (int i=0;i<16;i++) s_M[i]=M[i];
  }
  __syncthreads();

  // ---- phase 0 ----
  float gold = 0.f;
  {
    const int t0    = tid<<1;
    const int gbase = b*TT + (p<<9) + t0;
    float2 bb2 = *reinterpret_cast<const float2*>(bias + gbase);
    int2  sen2 = *reinterpret_cast<const int2*>(sentence + gbase);
    int2  tg2  = *reinterpret_cast<const int2*>(tags + gbase);
    float4 ftA = *reinterpret_cast<const float4*>(out_table + (size_t)sen2.x*4);
    float4 ftB = *reinterpret_cast<const float4*>(out_table + (size_t)sen2.y*4);

    int pv0;
    if ((tid & 63)==0) pv0 = (p==0 && t0==0) ? 4 : tags[gbase-1];
    else               pv0 = __shfl_up(tg2.y, 1);

    #pragma unroll
    for (int e=0;e<2;e++){
      const int tl = t0 + e;
      float bb   = e ? bb2.y : bb2.x;
      float4 f4e = e ? ftB   : ftA;
      int tg     = e ? tg2.y : tg2.x;
      int pv     = e ? tg2.x : pv0;

      float bh = bb-0.5f;
      float y0=fexp2(bh*wc0); float sh0=bb*(y0-1.f)*frcp(y0+1.f);
      float y1=fexp2(bh*wc1); float sh1=bb*(y1-1.f)*frcp(y1+1.f);
      float y2=fexp2(bh*wc2); float sh2v=bb*(y2-1.f)*frcp(y2+1.f);
      float y3=fexp2(bh*wc3); float sh3=bb*(y3-1.f)*frcp(y3+1.f);
      float s20=sh0*INVLN2, s21=sh1*INVLN2, s22=sh2v*INVLN2, s23=sh3*INVLN2;
      float f20=f4e.x*INVLN2, f21=f4e.y*INVLN2, f22=f4e.z*INVLN2, f23=f4e.w*INVLN2;

      float ct  = fmaxf(fmaxf(f20,f21),fmaxf(f22,f23)) + T144;
      float off = 8.0f - ct;
      float o0=f20+off, o1=f21+off, o2=f22+off, o3=f23+off;
      float a00=fexp2(fmaf(M[ 0],s20,trans2[ 0]+o0));
      float a01=fexp2(fmaf(M[ 1],s21,trans2[ 1]+o0));
      float a02=fexp2(fmaf(M[ 2],s22,trans2[ 2]+o0));
      float a03=fexp2(fmaf(M[ 3],s23,trans2[ 3]+o0));
      float a10=fexp2(fmaf(M[ 4],s20,trans2[ 4]+o1));
      float a11=fexp2(fmaf(M[ 5],s21,trans2[ 5]+o1));
      float a12=fexp2(fmaf(M[ 6],s22,trans2[ 6]+o1));
      float a13=fexp2(fmaf(M[ 7],s23,trans2[ 7]+o1));
      float a20=fexp2(fmaf(M[ 8],s20,trans2[ 8]+o2));
      float a21=fexp2(fmaf(M[ 9],s21,trans2[ 9]+o2));
      float a22=fexp2(fmaf(M[10],s22,trans2[10]+o2));
      float a23=fexp2(fmaf(M[11],s23,trans2[11]+o2));
      float a30=fexp2(fmaf(M[12],s20,trans2[12]+o3));
      float a31=fexp2(fmaf(M[13],s21,trans2[13]+o3));
      float a32=fexp2(fmaf(M[14],s22,trans2[14]+o3));
      float a33=fexp2(fmaf(M[15],s23,trans2[15]+o3));

      unsigned d0=enc_lo(a00,a01,0u); d0=enc_hi(a02,a03,d0);
      unsigned d1=enc_lo(a10,a11,0u); d1=enc_hi(a12,a13,d1);
      unsigned d2=enc_lo(a20,a21,0u); d2=enc_hi(a22,a23,d2);
      unsigned d3=enc_lo(a30,a31,0u); d3=enc_hi(a32,a33,d3);
      int g = (tl ^ ((tl>>3)&7)) << 4;
      *reinterpret_cast<uint4*>(s_te+g) = make_uint4(d0,d1,d2,d3);
      s_c[tl] = ct;

      float term;
      if (pv>=4){
        term = s_tr[tg*6+4];
      } else {
        float shp=(pv==0)?sh0:(pv==1)?sh1:(pv==2)?sh2v:sh3;
        term = s_tr[tg*6+pv] + shp*s_M[tg*4+pv];
      }
      term += (tg==0)?f4e.x:(tg==1)?f4e.y:(tg==2)?f4e.z:f4e.w;
      if (p==3 && tl==511) term += s_tr[30+tg];
      gold += term;
    }
    if (p==0 && tid==0){
      *reinterpret_cast<uint4*>(s_te) = make_uint4(0x38u,0x3800u,0x380000u,0x38000000u);
      s_c[0] = 8.0f;
    }
  }
  #pragma unroll
  for (int off=32; off>0; off>>=1) gold += __shfl_down(gold, off);
  if ((tid & 63)==0) s_wgold[tid>>6] = gold;
  __syncthreads();

  // ---- phase 1: 64 chunks x 8 steps ----
  {
    int c = tid>>2, j = tid&3;
    int t0c = c<<3;
    int K = c & 7;
    float p0=(j==0)?1.f:0.f, p1=(j==1)?1.f:0.f, p2=(j==2)?1.f:0.f, p3=(j==3)?1.f:0.f;
    #pragma unroll
    for (int s=0;s<8;s++){
      int g = ((t0c+s) ^ K) << 4;
      uint4 q = *reinterpret_cast<const uint4*>(s_te + g);
      float e0,e1,e2,e3;
      dec_lo(q.x,e0,e1); dec_hi(q.x,e2,e3);
      float n0 = fmaf(e0,p0, e1*p1); n0 = fmaf(e2,p2,n0); n0 = fmaf(e3,p3,n0);
      dec_lo(q.y,e0,e1); dec_hi(q.y,e2,e3);
      float n1 = fmaf(e0,p0, e1*p1); n1 = fmaf(e2,p2,n1); n1 = fmaf(e3,p3,n1);
      dec_lo(q.z,e0,e1); dec_hi(q.z,e2,e3);
      float n2 = fmaf(e0,p0, e1*p1); n2 = fmaf(e2,p2,n2); n2 = fmaf(e3,p3,n2);
      dec_lo(q.w,e0,e1); dec_hi(q.w,e2,e3);
      float n3 = fmaf(e0,p0, e1*p1); n3 = fmaf(e2,p2,n3); n3 = fmaf(e3,p3,n3);
      p0=n0; p1=n1; p2=n2; p3=n3;
    }
    float sum = fmaxf((p0+p1)+(p2+p3), 1e-30f);
    float inv = frcp(sum);
    const float4* cp = reinterpret_cast<const float4*>(s_c + t0c);
    float4 ca=cp[0], cb=cp[1];
    float L = flog2(sum)
            + ((ca.x+ca.y)+(ca.z+ca.w)) + ((cb.x+cb.y)+(cb.z+cb.w)) - 64.0f;
    s_PAm[c*16 + 0*4 + j] = p0*inv;
    s_PAm[c*16 + 1*4 + j] = p1*inv;
    s_PAm[c*16 + 2*4 + j] = p2*inv;
    s_PAm[c*16 + 3*4 + j] = p3*inv;
    s_PAs[c*4 + j] = L;
  }
  __syncthreads();

  // ---- phase 2: tree combine 64 -> 1 ----
  float *srcM = s_PAm, *srcS = s_PAs, *dstM = s_PBm, *dstS = s_PBs;
  #pragma unroll 1
  for (int n=32; n>=1; n>>=1){
    if (tid < n*4){
      int q = tid>>2, j = tid&3;
      const float* Am = srcM + (2*q)*16;
      const float* As = srcS + (2*q)*4;
      const float* Bm = Am + 16;
      const float* Bs = As + 4;
      float b0=Bs[0], b1=Bs[1], b2=Bs[2], b3=Bs[3];
      float m = fmaxf(fmaxf(b0,b1), fmaxf(b2,b3));
      float a0 = Am[0*4+j]*fexp2(b0-m);
      float a1 = Am[1*4+j]*fexp2(b1-m);
      float a2 = Am[2*4+j]*fexp2(b2-m);
      float a3 = Am[3*4+j]*fexp2(b3-m);
      float c0 = fmaf(Bm[ 0],a0, fmaf(Bm[ 1],a1, fmaf(Bm[ 2],a2, Bm[ 3]*a3)));
      float c1 = fmaf(Bm[ 4],a0, fmaf(Bm[ 5],a1, fmaf(Bm[ 6],a2, Bm[ 7]*a3)));
      float c2 = fmaf(Bm[ 8],a0, fmaf(Bm[ 9],a1, fmaf(Bm[10],a2, Bm[11]*a3)));
      float c3 = fmaf(Bm[12],a0, fmaf(Bm[13],a1, fmaf(Bm[14],a2, Bm[15]*a3)));
      float ssum = fmaxf((c0+c1)+(c2+c3), 1e-37f);
      float inv = frcp(ssum);
      dstM[q*16+0*4+j] = c0*inv;
      dstM[q*16+1*4+j] = c1*inv;
      dstM[q*16+2*4+j] = c2*inv;
      dstM[q*16+3*4+j] = c3*inv;
      dstS[q*4+j] = m + As[j] + flog2(ssum);
    }
    __syncthreads();
    float* tm;
    tm=srcM; srcM=dstM; dstM=tm;
    tm=srcS; srcS=dstS; dstS=tm;
  }

  // ---- publish: 20 floats + gold (plain stores; kernel boundary syncs) ----
  const int idx = (b<<2) | p;
  if (tid < 16)      partM[idx*20 + tid] = srcM[tid];
  else if (tid < 20) partM[idx*20 + tid] = srcS[tid-16];
  if (tid == 32)
    partG[idx] = ((s_wgold[0]+s_wgold[1])+(s_wgold[2]+s_wgold[3]));
}

// Kernel 2: 4 threads per dialog combine the 4 parts and finish the NLL.
__global__ __launch_bounds__(256) void crf_final(
    const float* __restrict__ trans,
    const float* __restrict__ out_table,
    const int*   __restrict__ sentence,
    const float* __restrict__ partM,
    const float* __restrict__ partG,
    float* __restrict__ out)
{
  constexpr float INVLN2 = 1.4426950408889634f;
  constexpr float LN2    = 0.6931471805599453f;
  const int tid = threadIdx.x;
  const int j   = tid & 3;
  const int dd  = tid >> 2;                 // dialog-in-block 0..63
  const int d   = (blockIdx.x<<6) + dd;     // dialog id

  __shared__ float s_m[64][21];             // 16 matrix + 4 scales (+1 pad)

  const float* P0 = partM + (size_t)(d<<2)*20;
  float c0=P0[0+j], c1=P0[4+j], c2=P0[8+j], c3=P0[12+j];
  float Lc=P0[16+j];
  #pragma unroll
  for (int q=1;q<4;q++){
    const float* Bq = partM + (size_t)((d<<2)+q)*20;
    float b0=Bq[16], b1=Bq[17], b2=Bq[18], b3=Bq[19];
    float m = fmaxf(fmaxf(b0,b1), fmaxf(b2,b3));
    float a0=c0*fexp2(b0-m), a1=c1*fexp2(b1-m),
          a2=c2*fexp2(b2-m), a3=c3*fexp2(b3-m);
    float n0 = fmaf(Bq[ 0],a0, fmaf(Bq[ 1],a1, fmaf(Bq[ 2],a2, Bq[ 3]*a3)));
    float n1 = fmaf(Bq[ 4],a0, fmaf(Bq[ 5],a1, fmaf(Bq[ 6],a2, Bq[ 7]*a3)));
    float n2 = fmaf(Bq[ 8],a0, fmaf(Bq[ 9],a1, fmaf(Bq[10],a2, Bq[11]*a3)));
    float n3 = fmaf(Bq[12],a0, fmaf(Bq[13],a1, fmaf(Bq[14],a2, Bq[15]*a3)));
    float ss = fmaxf((n0+n1)+(n2+n3), 1e-37f);
    float iv = frcp(ss);
    c0=n0*iv; c1=n1*iv; c2=n2*iv; c3=n3*iv;
    Lc += m + flog2(ss);
  }
  s_m[dd][0+j]=c0; s_m[dd][4+j]=c1; s_m[dd][8+j]=c2; s_m[dd][12+j]=c3;
  s_m[dd][16+j]=Lc;
  __syncthreads();

  if (j==0){
    const float* Pf = s_m[dd];
    const float* Ls = s_m[dd]+16;
    int s0 = sentence[(size_t)d*TT];
    float4 f0 = *reinterpret_cast<const float4*>(out_table + (size_t)s0*4);
    float a0 = (trans[ 4] + f0.x)*INVLN2;
    float a1 = (trans[10] + f0.y)*INVLN2;
    float a2 = (trans[16] + f0.z)*INVLN2;
    float a3 = (trans[22] + f0.w)*INVLN2;
    float u0 = Ls[0]+a0, u1 = Ls[1]+a1, u2 = Ls[2]+a2, u3 = Ls[3]+a3;
    float m2 = fmaxf(fmaxf(u0,u1), fmaxf(u2,u3));
    float e0 = fexp2(u0-m2), e1 = fexp2(u1-m2), e2 = fexp2(u2-m2), e3 = fexp2(u3-m2);
    float v0 = fmaf(Pf[ 0],e0, fmaf(Pf[ 1],e1, fmaf(Pf[ 2],e2, Pf[ 3]*e3)));
    float v1 = fmaf(Pf[ 4],e0, fmaf(Pf[ 5],e1, fmaf(Pf[ 6],e2, Pf[ 7]*e3)));
    float v2 = fmaf(Pf[ 8],e0, fmaf(Pf[ 9],e1, fmaf(Pf[10],e2, Pf[11]*e3)));
    float v3 = fmaf(Pf[12],e0, fmaf(Pf[13],e1, fmaf(Pf[14],e2, Pf[15]*e3)));
    float n0 = flog2(v0)+m2, n1 = flog2(v1)+m2, n2 = flog2(v2)+m2, n3 = flog2(v3)+m2;
    float fwd2 = lse2_4(n0+trans[30]*INVLN2, n1+trans[31]*INVLN2,
                        n2+trans[32]*INVLN2, n3+trans[33]*INVLN2);
    const float* Gp = partG + (size_t)(d<<2);
    float g = (Gp[0]+Gp[1])+(Gp[2]+Gp[3]);
    out[d] = fwd2*LN2 - g;
  }
}

extern "C" void kernel_launch(void* const* d_in, const int* in_sizes, int n_in,
                              void* d_out, int out_size, void* d_ws, size_t ws_size,
                              hipStream_t stream) {
  const float* trans     = (const float*)d_in[0];
  const float* w         = (const float*)d_in[1];
  const float* mult      = (const float*)d_in[2];
  const float* out_table = (const float*)d_in[3];
  const float* bias      = (const float*)d_in[4];
  const int*   sentence  = (const int*)d_in[5];
  const int*   tags      = (const int*)d_in[6];
  float* partM = (float*)d_ws;
  float* partG = (float*)((char*)d_ws + BB*4*20*sizeof(float));
  crf_part<<<BB*4, 256, 0, stream>>>(trans, w, mult, out_table, bias, sentence, tags,
                                     partM, partG);
  crf_final<<<BB/64, 256, 0, stream>>>(trans, out_table, sentence, partM, partG,
                                       (float*)d_out);
}

// Round 9
// 21.216 us; speedup vs baseline: 9.3462x; 1.0354x over previous
//
#include <hip/hip_runtime.h>

#define TT 2048
#define BB 512

typedef float f2 __attribute__((ext_vector_type(2)));
__device__ __forceinline__ f2 mk2(float v){ f2 r; r.x=v; r.y=v; return r; }

#if __has_builtin(__builtin_elementwise_fma)
#define FMA2(a,b,c) __builtin_elementwise_fma((a),(b),(c))
#else
#define FMA2(a,b,c) ((a)*(b)+(c))
#endif

#if __has_builtin(__builtin_amdgcn_exp2f)
__device__ __forceinline__ float fexp2(float x){ return __builtin_amdgcn_exp2f(x); }
#else
__device__ __forceinline__ float fexp2(float x){ return exp2f(x); }
#endif
#if __has_builtin(__builtin_amdgcn_logf)
__device__ __forceinline__ float flog2(float x){ return __builtin_amdgcn_logf(x); }
#else
__device__ __forceinline__ float flog2(float x){ return log2f(x); }
#endif
__device__ __forceinline__ float frcp(float x){ return __builtin_amdgcn_rcpf(x); }

// ---- fp8 e4m3 pack/unpack (OCP, gfx950 HW cvt) ----
#if __has_builtin(__builtin_amdgcn_cvt_pk_fp8_f32) && __has_builtin(__builtin_amdgcn_cvt_pk_f32_fp8)
__device__ __forceinline__ unsigned enc_lo(float a,float b,unsigned old){
  return (unsigned)__builtin_amdgcn_cvt_pk_fp8_f32(a,b,(int)old,false);
}
__device__ __forceinline__ unsigned enc_hi(float a,float b,unsigned old){
  return (unsigned)__builtin_amdgcn_cvt_pk_fp8_f32(a,b,(int)old,true);
}
__device__ __forceinline__ f2 dec_lo2(unsigned w){
  auto r=__builtin_amdgcn_cvt_pk_f32_fp8((int)w,false); f2 o; o.x=r[0]; o.y=r[1]; return o;
}
__device__ __forceinline__ f2 dec_hi2(unsigned w){
  auto r=__builtin_amdgcn_cvt_pk_f32_fp8((int)w,true); f2 o; o.x=r[0]; o.y=r[1]; return o;
}
#else
__device__ __forceinline__ unsigned enc1(float x){
  if (!(x > 0x1p-10f)) return 0u;
  unsigned b = __float_as_uint(x) + 0x80000u;
  int e = (int)((b>>23)&0xFF) - 127;
  if (e < -6){ int m = (int)(x*512.0f + 0.5f); return (unsigned)m; }
  if (e > 8) return 0x7Eu;
  return (unsigned)(((e+7)<<3) | ((b>>20)&7));
}
__device__ __forceinline__ float dec1(unsigned byte){
  unsigned e=(byte>>3)&0xF, m=byte&7;
  if (e==0) return (float)m * 0x1p-9f;
  return __uint_as_float(((e+120u)<<23)|(m<<20));
}
__device__ __forceinline__ unsigned enc_lo(float a,float b,unsigned old){
  return (old & 0xFFFF0000u) | enc1(a) | (enc1(b)<<8);
}
__device__ __forceinline__ unsigned enc_hi(float a,float b,unsigned old){
  return (old & 0x0000FFFFu) | (enc1(a)<<16) | (enc1(b)<<24);
}
__device__ __forceinline__ f2 dec_lo2(unsigned w){ f2 o; o.x=dec1(w&0xFF); o.y=dec1((w>>8)&0xFF); return o; }
__device__ __forceinline__ f2 dec_hi2(unsigned w){ f2 o; o.x=dec1((w>>16)&0xFF); o.y=dec1(w>>24); return o; }
#endif

__device__ __forceinline__ float lse2_4(float x0,float x1,float x2,float x3){
  float m = fmaxf(fmaxf(x0,x1),fmaxf(x2,x3));
  float e = fexp2(x0-m)+fexp2(x1-m)+fexp2(x2-m)+fexp2(x3-m);
  return m + flog2(e);
}

// Kernel 1: one dialog = 4 blocks of 256 threads; each block reduces 512
// timesteps to a 4x4 prob-matrix + 4 log2-scales + gold partial -> d_ws.
__global__ __launch_bounds__(256) void crf_part(
    const float* __restrict__ trans,      // [6,6]
    const float* __restrict__ w,          // [4]
    const float* __restrict__ mult,       // [4,4]
    const float* __restrict__ out_table,  // [V,4]
    const float* __restrict__ bias,       // [B,T]
    const int*   __restrict__ sentence,   // [B,T]
    const int*   __restrict__ tags,       // [B,T]
    float* __restrict__ partM,            // [B][4][20]
    float* __restrict__ partG)            // [B][4]
{
  constexpr float INVLN2 = 1.4426950408889634f;
  const int blk = blockIdx.x;
  const int b   = blk >> 2;
  const int p   = blk & 3;
  const int tid = threadIdx.x;

  __shared__ __align__(16) char  s_te[8192];   // fp8 Te COLUMN-major words
  __shared__ float s_PAm[64*16];
  __shared__ float s_PAs[64*4];
  __shared__ float s_M[16];
  __shared__ float s_tr[36];
  __shared__ float s_wgold[4];
  float* s_PBm = (float*)s_te;                 // aliased after phase-1 reads
  float* s_PBs = (float*)(s_te + 4096);

  // trans2: wave-uniform (compiler keeps in SGPR-adjacent form)
  float trans2[16]; float t2max = -1e30f;
  #pragma unroll
  for (int i=0;i<4;i++)
    #pragma unroll
    for (int k=0;k<4;k++){
      float v = trans[i*6+k]*INVLN2;
      trans2[i*4+k] = v; t2max = fmaxf(t2max, v);
    }
  const float T144 = t2max + 1.4427f;

  // M: lane-parallel (1 exp2) then readlane-broadcast to uniform regs
  float M[16];
  {
    int l = tid & 15;
    float mv = fexp2(mult[l]*INVLN2);
    float s1 = mv + __shfl_xor(mv, 4);
    float cs = s1 + __shfl_xor(s1, 8);
    float Ml = ((l>>2)==(l&3)) ? -1.f : mv*frcp(cs);
    if (tid < 16) s_M[tid] = Ml;
    int mi = __float_as_int(Ml);
    #pragma unroll
    for (int i=0;i<16;i++)
      M[i] = __int_as_float(__builtin_amdgcn_readlane(mi, i));
  }
  const float wc0=w[0]*2.f*INVLN2, wc1=w[1]*2.f*INVLN2,
              wc2=w[2]*2.f*INVLN2, wc3=w[3]*2.f*INVLN2;
  if (tid<36) s_tr[tid]=trans[tid];
  __syncthreads();

  // ---- phase 0: 2 consecutive t/thread; fp8 Te (col-major) + gold ----
  float gold = 0.f;
  float cts;
  {
    const int t0    = tid<<1;
    const int gbase = b*TT + (p<<9) + t0;
    float2 bb2 = *reinterpret_cast<const float2*>(bias + gbase);
    int2  sen2 = *reinterpret_cast<const int2*>(sentence + gbase);
    int2  tg2  = *reinterpret_cast<const int2*>(tags + gbase);
    float4 ftA = *reinterpret_cast<const float4*>(out_table + (size_t)sen2.x*4);
    float4 ftB = *reinterpret_cast<const float4*>(out_table + (size_t)sen2.y*4);

    int pv0;
    if ((tid & 63)==0) pv0 = (p==0 && t0==0) ? 4 : tags[gbase-1];
    else               pv0 = __shfl_up(tg2.y, 1);

    float ctv[2];
    #pragma unroll
    for (int e=0;e<2;e++){
      const int tl = t0 + e;
      float bb   = e ? bb2.y : bb2.x;
      float4 f4e = e ? ftB   : ftA;
      int tg     = e ? tg2.y : tg2.x;
      int pv     = e ? tg2.x : pv0;

      float bh = bb-0.5f;
      float y0=fexp2(bh*wc0); float sh0=bb*(y0-1.f)*frcp(y0+1.f);
      float y1=fexp2(bh*wc1); float sh1=bb*(y1-1.f)*frcp(y1+1.f);
      float y2=fexp2(bh*wc2); float sh2v=bb*(y2-1.f)*frcp(y2+1.f);
      float y3=fexp2(bh*wc3); float sh3=bb*(y3-1.f)*frcp(y3+1.f);
      float s20=sh0*INVLN2, s21=sh1*INVLN2, s22=sh2v*INVLN2, s23=sh3*INVLN2;
      float f20=f4e.x*INVLN2, f21=f4e.y*INVLN2, f22=f4e.z*INVLN2, f23=f4e.w*INVLN2;

      float ct  = fmaxf(fmaxf(f20,f21),fmaxf(f22,f23)) + T144;
      float off = 8.0f - ct;
      float o0=f20+off, o1=f21+off, o2=f22+off, o3=f23+off;
      float a00=fexp2(fmaf(M[ 0],s20,trans2[ 0]+o0));
      float a01=fexp2(fmaf(M[ 1],s21,trans2[ 1]+o0));
      float a02=fexp2(fmaf(M[ 2],s22,trans2[ 2]+o0));
      float a03=fexp2(fmaf(M[ 3],s23,trans2[ 3]+o0));
      float a10=fexp2(fmaf(M[ 4],s20,trans2[ 4]+o1));
      float a11=fexp2(fmaf(M[ 5],s21,trans2[ 5]+o1));
      float a12=fexp2(fmaf(M[ 6],s22,trans2[ 6]+o1));
      float a13=fexp2(fmaf(M[ 7],s23,trans2[ 7]+o1));
      float a20=fexp2(fmaf(M[ 8],s20,trans2[ 8]+o2));
      float a21=fexp2(fmaf(M[ 9],s21,trans2[ 9]+o2));
      float a22=fexp2(fmaf(M[10],s22,trans2[10]+o2));
      float a23=fexp2(fmaf(M[11],s23,trans2[11]+o2));
      float a30=fexp2(fmaf(M[12],s20,trans2[12]+o3));
      float a31=fexp2(fmaf(M[13],s21,trans2[13]+o3));
      float a32=fexp2(fmaf(M[14],s22,trans2[14]+o3));
      float a33=fexp2(fmaf(M[15],s23,trans2[15]+o3));

      // COLUMN-major words: word k = {T0k,T1k,T2k,T3k}
      unsigned d0=enc_lo(a00,a10,0u); d0=enc_hi(a20,a30,d0);
      unsigned d1=enc_lo(a01,a11,0u); d1=enc_hi(a21,a31,d1);
      unsigned d2=enc_lo(a02,a12,0u); d2=enc_hi(a22,a32,d2);
      unsigned d3=enc_lo(a03,a13,0u); d3=enc_hi(a23,a33,d3);
      int g = (tl ^ ((tl>>3)&7)) << 4;
      *reinterpret_cast<uint4*>(s_te+g) = make_uint4(d0,d1,d2,d3);
      ctv[e] = ct;

      float term;
      if (pv>=4){
        term = s_tr[tg*6+4];
      } else {
        float shp=(pv==0)?sh0:(pv==1)?sh1:(pv==2)?sh2v:sh3;
        term = s_tr[tg*6+pv] + shp*s_M[tg*4+pv];
      }
      term += (tg==0)?f4e.x:(tg==1)?f4e.y:(tg==2)?f4e.z:f4e.w;
      if (p==3 && tl==511) term += s_tr[30+tg];
      gold += term;
    }
    if (p==0 && tid==0){   // plant identity at t=0 (col-major identity = same words)
      *reinterpret_cast<uint4*>(s_te) = make_uint4(0x38u,0x3800u,0x380000u,0x38000000u);
      ctv[0] = 8.0f;
    }
    cts = ctv[0] + ctv[1];
  }
  #pragma unroll
  for (int off=32; off>0; off>>=1) gold += __shfl_down(gold, off);
  if ((tid & 63)==0) s_wgold[tid>>6] = gold;
  // per-chunk normalizer sum: chunk c = lanes 4c..4c+3 hold its 8 ct values
  float cpair = cts + __shfl_xor(cts, 1);
  float csum  = cpair + __shfl_xor(cpair, 2);
  __syncthreads();

  // ---- phase 1: 64 chunks x 8 steps; packed-f32 matvec ----
  {
    int c = tid>>2, j = tid&3;
    int t0c = c<<3;
    int K = c & 7;
    f2 a01, a23;
    a01.x = (j==0)?1.f:0.f; a01.y = (j==1)?1.f:0.f;
    a23.x = (j==2)?1.f:0.f; a23.y = (j==3)?1.f:0.f;
    #pragma unroll
    for (int s=0;s<8;s++){
      int g = ((t0c+s) ^ K) << 4;
      uint4 q = *reinterpret_cast<const uint4*>(s_te + g);
      float p0=a01.x, p1=a01.y, p2=a23.x, p3=a23.y;
      f2 n01 = dec_lo2(q.x)*mk2(p0);
      f2 n23 = dec_hi2(q.x)*mk2(p0);
      n01 = FMA2(dec_lo2(q.y), mk2(p1), n01);
      n23 = FMA2(dec_hi2(q.y), mk2(p1), n23);
      n01 = FMA2(dec_lo2(q.z), mk2(p2), n01);
      n23 = FMA2(dec_hi2(q.z), mk2(p2), n23);
      n01 = FMA2(dec_lo2(q.w), mk2(p3), n01);
      n23 = FMA2(dec_hi2(q.w), mk2(p3), n23);
      a01 = n01; a23 = n23;
    }
    float sum = fmaxf((a01.x+a01.y)+(a23.x+a23.y), 1e-30f);
    float inv = frcp(sum);
    float L = flog2(sum) + csum - 64.0f;
    s_PAm[c*16 + 0*4 + j] = a01.x*inv;
    s_PAm[c*16 + 1*4 + j] = a01.y*inv;
    s_PAm[c*16 + 2*4 + j] = a23.x*inv;
    s_PAm[c*16 + 3*4 + j] = a23.y*inv;
    s_PAs[c*4 + j] = L;
  }
  __syncthreads();   // all s_te reads done before PB alias writes

  // ---- phase 2: one block-wide level (64->32), then wave-0-only tail ----
  if (tid < 128){
    int q = tid>>2, j = tid&3;
    const float* Am = s_PAm + (2*q)*16;
    const float* As = s_PAs + (2*q)*4;
    const float* Bm = Am + 16;
    const float* Bs = As + 4;
    float b0=Bs[0], b1=Bs[1], b2=Bs[2], b3=Bs[3];
    float m = fmaxf(fmaxf(b0,b1), fmaxf(b2,b3));
    float a0 = Am[0*4+j]*fexp2(b0-m);
    float a1 = Am[1*4+j]*fexp2(b1-m);
    float a2 = Am[2*4+j]*fexp2(b2-m);
    float a3 = Am[3*4+j]*fexp2(b3-m);
    float c0 = fmaf(Bm[ 0],a0, fmaf(Bm[ 1],a1, fmaf(Bm[ 2],a2, Bm[ 3]*a3)));
    float c1 = fmaf(Bm[ 4],a0, fmaf(Bm[ 5],a1, fmaf(Bm[ 6],a2, Bm[ 7]*a3)));
    float c2 = fmaf(Bm[ 8],a0, fmaf(Bm[ 9],a1, fmaf(Bm[10],a2, Bm[11]*a3)));
    float c3 = fmaf(Bm[12],a0, fmaf(Bm[13],a1, fmaf(Bm[14],a2, Bm[15]*a3)));
    float ssum = fmaxf((c0+c1)+(c2+c3), 1e-37f);
    float inv = frcp(ssum);
    s_PBm[q*16+0*4+j] = c0*inv;
    s_PBm[q*16+1*4+j] = c1*inv;
    s_PBm[q*16+2*4+j] = c2*inv;
    s_PBm[q*16+3*4+j] = c3*inv;
    s_PBs[q*4+j] = m + As[j] + flog2(ssum);
  }
  __syncthreads();

  if (tid < 64){
    float *srcM = s_PBm, *srcS = s_PBs, *dstM = s_PAm, *dstS = s_PAs;
    #pragma unroll 1
    for (int n=16; n>=1; n>>=1){
      if (tid < n*4){
        int q = tid>>2, j = tid&3;
        const float* Am = srcM + (2*q)*16;
        const float* As = srcS + (2*q)*4;
        const float* Bm = Am + 16;
        const float* Bs = As + 4;
        float b0=Bs[0], b1=Bs[1], b2=Bs[2], b3=Bs[3];
        float m = fmaxf(fmaxf(b0,b1), fmaxf(b2,b3));
        float a0 = Am[0*4+j]*fexp2(b0-m);
        float a1 = Am[1*4+j]*fexp2(b1-m);
        float a2 = Am[2*4+j]*fexp2(b2-m);
        float a3 = Am[3*4+j]*fexp2(b3-m);
        float c0 = fmaf(Bm[ 0],a0, fmaf(Bm[ 1],a1, fmaf(Bm[ 2],a2, Bm[ 3]*a3)));
        float c1 = fmaf(Bm[ 4],a0, fmaf(Bm[ 5],a1, fmaf(Bm[ 6],a2, Bm[ 7]*a3)));
        float c2 = fmaf(Bm[ 8],a0, fmaf(Bm[ 9],a1, fmaf(Bm[10],a2, Bm[11]*a3)));
        float c3 = fmaf(Bm[12],a0, fmaf(Bm[13],a1, fmaf(Bm[14],a2, Bm[15]*a3)));
        float ssum = fmaxf((c0+c1)+(c2+c3), 1e-37f);
        float inv = frcp(ssum);
        dstM[q*16+0*4+j] = c0*inv;
        dstM[q*16+1*4+j] = c1*inv;
        dstM[q*16+2*4+j] = c2*inv;
        dstM[q*16+3*4+j] = c3*inv;
        dstS[q*4+j] = m + As[j] + flog2(ssum);
      }
      float* tm;
      tm=srcM; srcM=dstM; dstM=tm;
      tm=srcS; srcS=dstS; dstS=tm;
    }
    // publish (wave 0 only; 5 swaps from PBm -> final data in PAm == srcM)
    const int idx = (b<<2) | p;
    if (tid < 16)      partM[idx*20 + tid] = srcM[tid];
    else if (tid < 20) partM[idx*20 + tid] = srcS[tid-16];
    if (tid == 20)
      partG[idx] = ((s_wgold[0]+s_wgold[1])+(s_wgold[2]+s_wgold[3]));
  }
}

// Kernel 2: 4 threads per dialog combine the 4 parts and finish the NLL.
__global__ __launch_bounds__(256) void crf_final(
    const float* __restrict__ trans,
    const float* __restrict__ out_table,
    const int*   __restrict__ sentence,
    const float* __restrict__ partM,
    const float* __restrict__ partG,
    float* __restrict__ out)
{
  constexpr float INVLN2 = 1.4426950408889634f;
  constexpr float LN2    = 0.6931471805599453f;
  const int tid = threadIdx.x;
  const int j   = tid & 3;
  const int dd  = tid >> 2;
  const int d   = (blockIdx.x<<6) + dd;

  __shared__ float s_m[64][21];

  const float* P0 = partM + (size_t)(d<<2)*20;
  float c0=P0[0+j], c1=P0[4+j], c2=P0[8+j], c3=P0[12+j];
  float Lc=P0[16+j];
  #pragma unroll
  for (int q=1;q<4;q++){
    const float* Bq = partM + (size_t)((d<<2)+q)*20;
    float b0=Bq[16], b1=Bq[17], b2=Bq[18], b3=Bq[19];
    float m = fmaxf(fmaxf(b0,b1), fmaxf(b2,b3));
    float a0=c0*fexp2(b0-m), a1=c1*fexp2(b1-m),
          a2=c2*fexp2(b2-m), a3=c3*fexp2(b3-m);
    float n0 = fmaf(Bq[ 0],a0, fmaf(Bq[ 1],a1, fmaf(Bq[ 2],a2, Bq[ 3]*a3)));
    float n1 = fmaf(Bq[ 4],a0, fmaf(Bq[ 5],a1, fmaf(Bq[ 6],a2, Bq[ 7]*a3)));
    float n2 = fmaf(Bq[ 8],a0, fmaf(Bq[ 9],a1, fmaf(Bq[10],a2, Bq[11]*a3)));
    float n3 = fmaf(Bq[12],a0, fmaf(Bq[13],a1, fmaf(Bq[14],a2, Bq[15]*a3)));
    float ss = fmaxf((n0+n1)+(n2+n3), 1e-37f);
    float iv = frcp(ss);
    c0=n0*iv; c1=n1*iv; c2=n2*iv; c3=n3*iv;
    Lc += m + flog2(ss);
  }
  s_m[dd][0+j]=c0; s_m[dd][4+j]=c1; s_m[dd][8+j]=c2; s_m[dd][12+j]=c3;
  s_m[dd][16+j]=Lc;
  __syncthreads();

  if (j==0){
    const float* Pf = s_m[dd];
    const float* Ls = s_m[dd]+16;
    int s0 = sentence[(size_t)d*TT];
    float4 f0 = *reinterpret_cast<const float4*>(out_table + (size_t)s0*4);
    float a0 = (trans[ 4] + f0.x)*INVLN2;
    float a1 = (trans[10] + f0.y)*INVLN2;
    float a2 = (trans[16] + f0.z)*INVLN2;
    float a3 = (trans[22] + f0.w)*INVLN2;
    float u0 = Ls[0]+a0, u1 = Ls[1]+a1, u2 = Ls[2]+a2, u3 = Ls[3]+a3;
    float m2 = fmaxf(fmaxf(u0,u1), fmaxf(u2,u3));
    float e0 = fexp2(u0-m2), e1 = fexp2(u1-m2), e2 = fexp2(u2-m2), e3 = fexp2(u3-m2);
    float v0 = fmaf(Pf[ 0],e0, fmaf(Pf[ 1],e1, fmaf(Pf[ 2],e2, Pf[ 3]*e3)));
    float v1 = fmaf(Pf[ 4],e0, fmaf(Pf[ 5],e1, fmaf(Pf[ 6],e2, Pf[ 7]*e3)));
    float v2 = fmaf(Pf[ 8],e0, fmaf(Pf[ 9],e1, fmaf(Pf[10],e2, Pf[11]*e3)));
    float v3 = fmaf(Pf[12],e0, fmaf(Pf[13],e1, fmaf(Pf[14],e2, Pf[15]*e3)));
    float n0 = flog2(v0)+m2, n1 = flog2(v1)+m2, n2 = flog2(v2)+m2, n3 = flog2(v3)+m2;
    float fwd2 = lse2_4(n0+trans[30]*INVLN2, n1+trans[31]*INVLN2,
                        n2+trans[32]*INVLN2, n3+trans[33]*INVLN2);
    const float* Gp = partG + (size_t)(d<<2);
    float g = (Gp[0]+Gp[1])+(Gp[2]+Gp[3]);
    out[d] = fwd2*LN2 - g;
  }
}

extern "C" void kernel_launch(void* const* d_in, const int* in_sizes, int n_in,
                              void* d_out, int out_size, void* d_ws, size_t ws_size,
                              hipStream_t stream) {
  const float* trans     = (const float*)d_in[0];
  const float* w         = (const float*)d_in[1];
  const float* mult      = (const float*)d_in[2];
  const float* out_table = (const float*)d_in[3];
  const float* bias      = (const float*)d_in[4];
  const int*   sentence  = (const int*)d_in[5];
  const int*   tags      = (const int*)d_in[6];
  float* partM = (float*)d_ws;
  float* partG = (float*)((char*)d_ws + BB*4*20*sizeof(float));
  crf_part<<<BB*4, 256, 0, stream>>>(trans, w, mult, out_table, bias, sentence, tags,
                                     partM, partG);
  crf_final<<<BB/64, 256, 0, stream>>>(trans, out_table, sentence, partM, partG,
                                       (float*)d_out);
}

// Round 10
// 19.783 us; speedup vs baseline: 10.0230x; 1.0724x over previous
//
#include <hip/hip_runtime.h>

#define TT 2048
#define BB 512

typedef float f2 __attribute__((ext_vector_type(2)));
__device__ __forceinline__ f2 mk2(float v){ f2 r; r.x=v; r.y=v; return r; }

#if __has_builtin(__builtin_elementwise_fma)
#define FMA2(a,b,c) __builtin_elementwise_fma((a),(b),(c))
#else
#define FMA2(a,b,c) ((a)*(b)+(c))
#endif

#if __has_builtin(__builtin_amdgcn_exp2f)
__device__ __forceinline__ float fexp2(float x){ return __builtin_amdgcn_exp2f(x); }
#else
__device__ __forceinline__ float fexp2(float x){ return exp2f(x); }
#endif
#if __has_builtin(__builtin_amdgcn_logf)
__device__ __forceinline__ float flog2(float x){ return __builtin_amdgcn_logf(x); }
#else
__device__ __forceinline__ float flog2(float x){ return log2f(x); }
#endif
__device__ __forceinline__ float frcp(float x){ return __builtin_amdgcn_rcpf(x); }

// ---- fp8 e4m3 pack/unpack (OCP, gfx950 HW cvt) ----
#if __has_builtin(__builtin_amdgcn_cvt_pk_fp8_f32) && __has_builtin(__builtin_amdgcn_cvt_pk_f32_fp8)
__device__ __forceinline__ unsigned enc_lo(float a,float b,unsigned old){
  return (unsigned)__builtin_amdgcn_cvt_pk_fp8_f32(a,b,(int)old,false);
}
__device__ __forceinline__ unsigned enc_hi(float a,float b,unsigned old){
  return (unsigned)__builtin_amdgcn_cvt_pk_fp8_f32(a,b,(int)old,true);
}
__device__ __forceinline__ f2 dec_lo2(unsigned w){
  auto r=__builtin_amdgcn_cvt_pk_f32_fp8((int)w,false); f2 o; o.x=r[0]; o.y=r[1]; return o;
}
__device__ __forceinline__ f2 dec_hi2(unsigned w){
  auto r=__builtin_amdgcn_cvt_pk_f32_fp8((int)w,true); f2 o; o.x=r[0]; o.y=r[1]; return o;
}
#else
__device__ __forceinline__ unsigned enc1(float x){
  if (!(x > 0x1p-10f)) return 0u;
  unsigned b = __float_as_uint(x) + 0x80000u;
  int e = (int)((b>>23)&0xFF) - 127;
  if (e < -6){ int m = (int)(x*512.0f + 0.5f); return (unsigned)m; }
  if (e > 8) return 0x7Eu;
  return (unsigned)(((e+7)<<3) | ((b>>20)&7));
}
__device__ __forceinline__ float dec1(unsigned byte){
  unsigned e=(byte>>3)&0xF, m=byte&7;
  if (e==0) return (float)m * 0x1p-9f;
  return __uint_as_float(((e+120u)<<23)|(m<<20));
}
__device__ __forceinline__ unsigned enc_lo(float a,float b,unsigned old){
  return (old & 0xFFFF0000u) | enc1(a) | (enc1(b)<<8);
}
__device__ __forceinline__ unsigned enc_hi(float a,float b,unsigned old){
  return (old & 0x0000FFFFu) | (enc1(a)<<16) | (enc1(b)<<24);
}
__device__ __forceinline__ f2 dec_lo2(unsigned w){ f2 o; o.x=dec1(w&0xFF); o.y=dec1((w>>8)&0xFF); return o; }
__device__ __forceinline__ f2 dec_hi2(unsigned w){ f2 o; o.x=dec1((w>>16)&0xFF); o.y=dec1(w>>24); return o; }
#endif

__device__ __forceinline__ float lse2_4(float x0,float x1,float x2,float x3){
  float m = fmaxf(fmaxf(x0,x1),fmaxf(x2,x3));
  float e = fexp2(x0-m)+fexp2(x1-m)+fexp2(x2-m)+fexp2(x3-m);
  return m + flog2(e);
}

// One dialog per block, 1024 threads (2 t/thread). Single dispatch.
__global__ __launch_bounds__(1024) void crf_kernel(
    const float* __restrict__ trans,      // [6,6]
    const float* __restrict__ w,          // [4]
    const float* __restrict__ mult,       // [4,4]
    const float* __restrict__ out_table,  // [V,4]
    const float* __restrict__ bias,       // [B,T]
    const int*   __restrict__ sentence,   // [B,T]
    const int*   __restrict__ tags,       // [B,T]
    float* __restrict__ out)              // [B]
{
  constexpr float INVLN2 = 1.4426950408889634f;
  constexpr float LN2    = 0.6931471805599453f;
  const int b   = blockIdx.x;
  const int tid = threadIdx.x;

  __shared__ __align__(16) char  s_te[32768];  // fp8 Te col-major, granule = t^((t>>3)&7)
  __shared__ float s_PAm[256*16];              // 16 KB chunk matrices
  __shared__ float s_PAs[256*4];               //  4 KB chunk scales
  __shared__ float s_M[16];
  __shared__ float s_tr[36];
  __shared__ float s_wgold[16];
  float* s_PBm = (float*)s_te;                 // aliased after phase-1 reads (<=8KB)
  float* s_PBs = (float*)(s_te + 16384);       // (<=2KB)

  float trans2[16]; float t2max = -1e30f;
  #pragma unroll
  for (int i=0;i<4;i++)
    #pragma unroll
    for (int k=0;k<4;k++){
      float v = trans[i*6+k]*INVLN2;
      trans2[i*4+k] = v; t2max = fmaxf(t2max, v);
    }
  const float T144 = t2max + 1.4427f;

  // M: lane-parallel exp2 then readlane broadcast
  float M[16];
  {
    int l = tid & 15;
    float mv = fexp2(mult[l]*INVLN2);
    float s1 = mv + __shfl_xor(mv, 4);
    float cs = s1 + __shfl_xor(s1, 8);
    float Ml = ((l>>2)==(l&3)) ? -1.f : mv*frcp(cs);
    if (tid < 16) s_M[tid] = Ml;
    int mi = __float_as_int(Ml);
    #pragma unroll
    for (int i=0;i<16;i++)
      M[i] = __int_as_float(__builtin_amdgcn_readlane(mi, i));
  }
  const float wc0=w[0]*2.f*INVLN2, wc1=w[1]*2.f*INVLN2,
              wc2=w[2]*2.f*INVLN2, wc3=w[3]*2.f*INVLN2;
  if (tid<36) s_tr[tid]=trans[tid];
  __syncthreads();

  // ---- phase 0: 2 consecutive t/thread; fp8 Te (col-major) + gold ----
  float gold = 0.f;
  float cts;
  {
    const int t0    = tid<<1;
    const int gbase = b*TT + t0;
    float2 bb2 = *reinterpret_cast<const float2*>(bias + gbase);
    int2  sen2 = *reinterpret_cast<const int2*>(sentence + gbase);
    int2  tg2  = *reinterpret_cast<const int2*>(tags + gbase);
    float4 ftA = *reinterpret_cast<const float4*>(out_table + (size_t)sen2.x*4);
    float4 ftB = *reinterpret_cast<const float4*>(out_table + (size_t)sen2.y*4);

    int pv0;
    if ((tid & 63)==0) pv0 = (t0==0) ? 4 : tags[gbase-1];
    else               pv0 = __shfl_up(tg2.y, 1);

    float ctv[2];
    #pragma unroll
    for (int e=0;e<2;e++){
      const int tl = t0 + e;
      float bb   = e ? bb2.y : bb2.x;
      float4 f4e = e ? ftB   : ftA;
      int tg     = e ? tg2.y : tg2.x;
      int pv     = e ? tg2.x : pv0;

      float bh = bb-0.5f;
      float y0=fexp2(bh*wc0); float sh0=bb*(y0-1.f)*frcp(y0+1.f);
      float y1=fexp2(bh*wc1); float sh1=bb*(y1-1.f)*frcp(y1+1.f);
      float y2=fexp2(bh*wc2); float sh2v=bb*(y2-1.f)*frcp(y2+1.f);
      float y3=fexp2(bh*wc3); float sh3=bb*(y3-1.f)*frcp(y3+1.f);
      float s20=sh0*INVLN2, s21=sh1*INVLN2, s22=sh2v*INVLN2, s23=sh3*INVLN2;
      float f20=f4e.x*INVLN2, f21=f4e.y*INVLN2, f22=f4e.z*INVLN2, f23=f4e.w*INVLN2;

      float ct  = fmaxf(fmaxf(f20,f21),fmaxf(f22,f23)) + T144;
      float off = 8.0f - ct;
      float o0=f20+off, o1=f21+off, o2=f22+off, o3=f23+off;
      float a00=fexp2(fmaf(M[ 0],s20,trans2[ 0]+o0));
      float a01=fexp2(fmaf(M[ 1],s21,trans2[ 1]+o0));
      float a02=fexp2(fmaf(M[ 2],s22,trans2[ 2]+o0));
      float a03=fexp2(fmaf(M[ 3],s23,trans2[ 3]+o0));
      float a10=fexp2(fmaf(M[ 4],s20,trans2[ 4]+o1));
      float a11=fexp2(fmaf(M[ 5],s21,trans2[ 5]+o1));
      float a12=fexp2(fmaf(M[ 6],s22,trans2[ 6]+o1));
      float a13=fexp2(fmaf(M[ 7],s23,trans2[ 7]+o1));
      float a20=fexp2(fmaf(M[ 8],s20,trans2[ 8]+o2));
      float a21=fexp2(fmaf(M[ 9],s21,trans2[ 9]+o2));
      float a22=fexp2(fmaf(M[10],s22,trans2[10]+o2));
      float a23=fexp2(fmaf(M[11],s23,trans2[11]+o2));
      float a30=fexp2(fmaf(M[12],s20,trans2[12]+o3));
      float a31=fexp2(fmaf(M[13],s21,trans2[13]+o3));
      float a32=fexp2(fmaf(M[14],s22,trans2[14]+o3));
      float a33=fexp2(fmaf(M[15],s23,trans2[15]+o3));

      // COLUMN-major words: word k = {T0k,T1k,T2k,T3k}
      unsigned d0=enc_lo(a00,a10,0u); d0=enc_hi(a20,a30,d0);
      unsigned d1=enc_lo(a01,a11,0u); d1=enc_hi(a21,a31,d1);
      unsigned d2=enc_lo(a02,a12,0u); d2=enc_hi(a22,a32,d2);
      unsigned d3=enc_lo(a03,a13,0u); d3=enc_hi(a23,a33,d3);
      int g = (tl ^ ((tl>>3)&7)) << 4;
      *reinterpret_cast<uint4*>(s_te+g) = make_uint4(d0,d1,d2,d3);
      ctv[e] = ct;

      float term;
      if (pv>=4){                              // only at t==0
        term = s_tr[tg*6+4];
      } else {
        float shp=(pv==0)?sh0:(pv==1)?sh1:(pv==2)?sh2v:sh3;
        term = s_tr[tg*6+pv] + shp*s_M[tg*4+pv];
      }
      term += (tg==0)?f4e.x:(tg==1)?f4e.y:(tg==2)?f4e.z:f4e.w;
      if (tl==TT-1) term += s_tr[30+tg];
      gold += term;
    }
    if (tid==0){   // plant identity at t=0
      *reinterpret_cast<uint4*>(s_te) = make_uint4(0x38u,0x3800u,0x380000u,0x38000000u);
      ctv[0] = 8.0f;
    }
    cts = ctv[0] + ctv[1];
  }
  #pragma unroll
  for (int off=32; off>0; off>>=1) gold += __shfl_down(gold, off);
  if ((tid & 63)==0) s_wgold[tid>>6] = gold;
  // chunk c = lanes 4c..4c+3 hold its 8 ct values (2 per lane)
  float cpair = cts + __shfl_xor(cts, 1);
  float csum  = cpair + __shfl_xor(cpair, 2);
  __syncthreads();

  // ---- phase 1: 256 chunks x 8 steps; packed-f32 matvec ----
  {
    int c = tid>>2, j = tid&3;
    int t0c = c<<3;
    int K = c & 7;
    f2 a01, a23;
    a01.x = (j==0)?1.f:0.f; a01.y = (j==1)?1.f:0.f;
    a23.x = (j==2)?1.f:0.f; a23.y = (j==3)?1.f:0.f;
    #pragma unroll
    for (int s=0;s<8;s++){
      int g = ((t0c+s) ^ K) << 4;
      uint4 q = *reinterpret_cast<const uint4*>(s_te + g);
      float p0=a01.x, p1=a01.y, p2=a23.x, p3=a23.y;
      f2 n01 = dec_lo2(q.x)*mk2(p0);
      f2 n23 = dec_hi2(q.x)*mk2(p0);
      n01 = FMA2(dec_lo2(q.y), mk2(p1), n01);
      n23 = FMA2(dec_hi2(q.y), mk2(p1), n23);
      n01 = FMA2(dec_lo2(q.z), mk2(p2), n01);
      n23 = FMA2(dec_hi2(q.z), mk2(p2), n23);
      n01 = FMA2(dec_lo2(q.w), mk2(p3), n01);
      n23 = FMA2(dec_hi2(q.w), mk2(p3), n23);
      a01 = n01; a23 = n23;
    }
    float sum = fmaxf((a01.x+a01.y)+(a23.x+a23.y), 1e-30f);
    float inv = frcp(sum);
    float L = flog2(sum) + csum - 64.0f;
    s_PAm[c*16 + 0*4 + j] = a01.x*inv;
    s_PAm[c*16 + 1*4 + j] = a01.y*inv;
    s_PAm[c*16 + 2*4 + j] = a23.x*inv;
    s_PAm[c*16 + 3*4 + j] = a23.y*inv;
    s_PAs[c*4 + j] = L;
  }
  __syncthreads();   // all s_te reads done before PB alias writes

  // ---- phase 2: block-wide levels 256->128->64->32, then wave-0 tail ----
  #define COMBINE(SRC_M,SRC_S,DST_M,DST_S,Q,J)                                   \
    { const float* Am = (SRC_M) + (2*(Q))*16;                                    \
      const float* As = (SRC_S) + (2*(Q))*4;                                     \
      const float* Bm = Am + 16;                                                 \
      const float* Bs = As + 4;                                                  \
      float b0=Bs[0], b1=Bs[1], b2=Bs[2], b3=Bs[3];                              \
      float m = fmaxf(fmaxf(b0,b1), fmaxf(b2,b3));                               \
      float a0 = Am[0*4+(J)]*fexp2(b0-m);                                        \
      float a1 = Am[1*4+(J)]*fexp2(b1-m);                                        \
      float a2 = Am[2*4+(J)]*fexp2(b2-m);                                        \
      float a3 = Am[3*4+(J)]*fexp2(b3-m);                                        \
      float c0 = fmaf(Bm[ 0],a0, fmaf(Bm[ 1],a1, fmaf(Bm[ 2],a2, Bm[ 3]*a3)));  \
      float c1 = fmaf(Bm[ 4],a0, fmaf(Bm[ 5],a1, fmaf(Bm[ 6],a2, Bm[ 7]*a3)));  \
      float c2 = fmaf(Bm[ 8],a0, fmaf(Bm[ 9],a1, fmaf(Bm[10],a2, Bm[11]*a3)));  \
      float c3 = fmaf(Bm[12],a0, fmaf(Bm[13],a1, fmaf(Bm[14],a2, Bm[15]*a3)));  \
      float ssum = fmaxf((c0+c1)+(c2+c3), 1e-37f);                               \
      float inv = frcp(ssum);                                                    \
      (DST_M)[(Q)*16+0*4+(J)] = c0*inv;                                          \
      (DST_M)[(Q)*16+1*4+(J)] = c1*inv;                                          \
      (DST_M)[(Q)*16+2*4+(J)] = c2*inv;                                          \
      (DST_M)[(Q)*16+3*4+(J)] = c3*inv;                                          \
      (DST_S)[(Q)*4+(J)] = m + As[(J)] + flog2(ssum); }

  if (tid < 512) COMBINE(s_PAm, s_PAs, s_PBm, s_PBs, (tid>>2), (tid&3));
  __syncthreads();
  if (tid < 256) COMBINE(s_PBm, s_PBs, s_PAm, s_PAs, (tid>>2), (tid&3));
  __syncthreads();
  if (tid < 128) COMBINE(s_PAm, s_PAs, s_PBm, s_PBs, (tid>>2), (tid&3));
  __syncthreads();

  if (tid < 64){
    // in-wave tail: 32 -> 1 (5 levels, lockstep, no barriers)
    float *srcM = s_PBm, *srcS = s_PBs, *dstM = s_PAm, *dstS = s_PAs;
    #pragma unroll 1
    for (int n=16; n>=1; n>>=1){
      if (tid < n*4) COMBINE(srcM, srcS, dstM, dstS, (tid>>2), (tid&3));
      float* tm;
      tm=srcM; srcM=dstM; dstM=tm;
      tm=srcS; srcS=dstS; dstS=tm;
    }
    if (tid==0){
      const float* Pf = srcM;   // total matrix for t=1..T-1
      const float* Ls = srcS;
      int s0 = sentence[(size_t)b*TT];
      float4 f0 = *reinterpret_cast<const float4*>(out_table + (size_t)s0*4);
      float a0 = (s_tr[ 4] + f0.x)*INVLN2;
      float a1 = (s_tr[10] + f0.y)*INVLN2;
      float a2 = (s_tr[16] + f0.z)*INVLN2;
      float a3 = (s_tr[22] + f0.w)*INVLN2;
      float u0 = Ls[0]+a0, u1 = Ls[1]+a1, u2 = Ls[2]+a2, u3 = Ls[3]+a3;
      float m2 = fmaxf(fmaxf(u0,u1), fmaxf(u2,u3));
      float e0 = fexp2(u0-m2), e1 = fexp2(u1-m2), e2 = fexp2(u2-m2), e3 = fexp2(u3-m2);
      float v0 = fmaf(Pf[ 0],e0, fmaf(Pf[ 1],e1, fmaf(Pf[ 2],e2, Pf[ 3]*e3)));
      float v1 = fmaf(Pf[ 4],e0, fmaf(Pf[ 5],e1, fmaf(Pf[ 6],e2, Pf[ 7]*e3)));
      float v2 = fmaf(Pf[ 8],e0, fmaf(Pf[ 9],e1, fmaf(Pf[10],e2, Pf[11]*e3)));
      float v3 = fmaf(Pf[12],e0, fmaf(Pf[13],e1, fmaf(Pf[14],e2, Pf[15]*e3)));
      float n0 = flog2(v0)+m2, n1 = flog2(v1)+m2, n2 = flog2(v2)+m2, n3 = flog2(v3)+m2;
      float fwd2 = lse2_4(n0+s_tr[30]*INVLN2, n1+s_tr[31]*INVLN2,
                          n2+s_tr[32]*INVLN2, n3+s_tr[33]*INVLN2);
      float g = 0.f;
      #pragma unroll
      for (int i=0;i<16;i++) g += s_wgold[i];
      out[b] = fwd2*LN2 - g;
    }
  }
}

extern "C" void kernel_launch(void* const* d_in, const int* in_sizes, int n_in,
                              void* d_out, int out_size, void* d_ws, size_t ws_size,
                              hipStream_t stream) {
  const float* trans     = (const float*)d_in[0];
  const float* w         = (const float*)d_in[1];
  const float* mult      = (const float*)d_in[2];
  const float* out_table = (const float*)d_in[3];
  const float* bias      = (const float*)d_in[4];
  const int*   sentence  = (const int*)d_in[5];
  const int*   tags      = (const int*)d_in[6];
  crf_kernel<<<BB, 1024, 0, stream>>>(trans, w, mult, out_table, bias, sentence, tags,
                                      (float*)d_out);
}